// Round 5
// baseline (278.446 us; speedup 1.0000x reference)
//
#include <hip/hip_runtime.h>

#define BATCH 16
#define LQ    1024
#define LK    1024
#define DD    512

typedef unsigned int u32;
typedef unsigned short ushort_t;
typedef short short8 __attribute__((ext_vector_type(8)));
typedef float f32x4 __attribute__((ext_vector_type(4)));

// ---------------------------------------------------------------------------
// split fp32 pair -> packed bf16 hi (truncation) and bf16 lo (= x - hi)
// ---------------------------------------------------------------------------
__device__ __forceinline__ void split2(float x0, float x1, u32& hp, u32& lp) {
    u32 u0 = __float_as_uint(x0), u1 = __float_as_uint(x1);
    hp = __builtin_amdgcn_perm(u1, u0, 0x07060302u);   // (bf16(x0), bf16(x1))
    float l0 = x0 - __uint_as_float(u0 & 0xffff0000u);
    float l1 = x1 - __uint_as_float(u1 & 0xffff0000u);
    lp = __builtin_amdgcn_perm(__float_as_uint(l1), __float_as_uint(l0), 0x07060302u);
}

// ---------------------------------------------------------------------------
// V [LK x DD] -> Vt [DD x LK], fp32, per batch. grid (DD/32, LK/32, BATCH)
// ---------------------------------------------------------------------------
__global__ __launch_bounds__(256) void transpose_v(const float* __restrict__ V,
                                                   float* __restrict__ Vt) {
    __shared__ float tile[32][33];
    const int b = blockIdx.z;
    const int c0 = blockIdx.x * 32;   // d
    const int r0 = blockIdx.y * 32;   // kv
    const int t = threadIdx.x;
    const int r = t >> 3, c4 = (t & 7) * 4;
    const float* Vb = V + (size_t)b * LK * DD;
    float4 f = *(const float4*)(Vb + (size_t)(r0 + r) * DD + c0 + c4);
    tile[r][c4 + 0] = f.x; tile[r][c4 + 1] = f.y;
    tile[r][c4 + 2] = f.z; tile[r][c4 + 3] = f.w;
    __syncthreads();
    const int n = t >> 3, k4 = (t & 7) * 4;
    float4 o = {tile[k4 + 0][n], tile[k4 + 1][n], tile[k4 + 2][n], tile[k4 + 3][n]};
    *(float4*)(Vt + (size_t)b * DD * LK + (size_t)(c0 + n) * LK + r0 + k4) = o;
}

// ---------------------------------------------------------------------------
// Split-bf16 MFMA GEMM with split-on-stage:
//   C[1024 x NG] = A[1024 x KG] * B[NG x KG]^T   per batch (fp32 in/out)
// 128x128 tile, BK=32, 4 waves. Staging: global->VGPR (coalesced dwordx4),
// hi/lo split ONCE per element, ds_write_b64 into a single 32 KB bf16 buffer.
// Next tile's loads are issued before the MFMA phase (VGPR prefetch), so the
// global latency hides under compute without LDS double-buffering.
//
// LDS: sm[4][128*32] bf16 comps {Ahi,Alo,Bhi,Blo}; rows 64 B = 4 chunks of
// 16 B, physical chunk = logical ^ (row&3):
//   - frag reads (ds_read_b128, chunk q at rows mf+16i): <=2-way = free
//   - staging writes (b64 halves): conflict-free
// ---------------------------------------------------------------------------
template <int KG, int NG>
__global__ __launch_bounds__(256) void gemm_stage_split(const float* __restrict__ A,
                                                        const float* __restrict__ B,
                                                        float* __restrict__ C) {
    __shared__ ushort_t sm[4][128 * 32];   // 32 KB total

    const int b   = blockIdx.z;
    const int bm0 = blockIdx.x * 128;
    const int bn0 = blockIdx.y * 128;
    const int tid = threadIdx.x;
    const int w   = tid >> 6;
    const int lane = tid & 63;

    // ---- staging assignment: wave 0/1 -> A rows [0,64)/[64,128); 2/3 -> B
    const int op   = w >> 1;
    const int woff = (w & 1) * 64;
    const int srow = woff + (lane >> 3);      // + 8t in the loop
    const int h    = lane & 7;                // 8-byte half-chunk within row
    const float* gsrc = (op == 0)
        ? A + (size_t)b * 1024 * KG + (size_t)(bm0 + srow) * KG
        : B + (size_t)b * NG * KG   + (size_t)(bn0 + srow) * KG;
    gsrc += h * 4;
    // LDS write base (ushorts): row srow, swizzled half-chunk h
    const int wbase = srow * 32 + ((h >> 1) ^ (srow & 3)) * 8 + (h & 1) * 4;
    ushort_t* wp_hi = &sm[op * 2 + 0][wbase];
    ushort_t* wp_lo = &sm[op * 2 + 1][wbase];

    // ---- fragment read offsets
    const int mf = lane & 15, q = lane >> 4;
    const int qx = (q ^ (mf & 3)) * 8;        // swizzled chunk offset (ushorts)
    const int wm = (w & 1) * 64, wn = (w >> 1) * 64;

    f32x4 acc[4][4] = {};
    float4 st[8];

    auto load_tile = [&](int k) {
#pragma unroll
        for (int t = 0; t < 8; ++t)
            st[t] = *(const float4*)(gsrc + k + (size_t)t * 8 * KG);
    };

    load_tile(0);
    for (int k0 = 0; k0 < KG; k0 += 32) {
        // split staged tile -> LDS (each row +8t, offset t*8rows*32 = t*256)
#pragma unroll
        for (int t = 0; t < 8; ++t) {
            u32 h01, h23, l01, l23;
            split2(st[t].x, st[t].y, h01, l01);
            split2(st[t].z, st[t].w, h23, l23);
            uint2 hv; hv.x = h01; hv.y = h23;
            uint2 lv; lv.x = l01; lv.y = l23;
            *(uint2*)(wp_hi + t * 256) = hv;
            *(uint2*)(wp_lo + t * 256) = lv;
        }
        if (k0 + 32 < KG) load_tile(k0 + 32);   // prefetch next tile into VGPRs
        __syncthreads();                         // LDS tile ready

        short8 ah[4], al[4];
#pragma unroll
        for (int i = 0; i < 4; ++i) {
            ah[i] = *(const short8*)&sm[0][(wm + mf + 16 * i) * 32 + qx];
            al[i] = *(const short8*)&sm[1][(wm + mf + 16 * i) * 32 + qx];
        }
#pragma unroll
        for (int j = 0; j < 4; ++j) {
            short8 bh = *(const short8*)&sm[2][(wn + mf + 16 * j) * 32 + qx];
            short8 bl = *(const short8*)&sm[3][(wn + mf + 16 * j) * 32 + qx];
#pragma unroll
            for (int i = 0; i < 4; ++i) {
                acc[i][j] = __builtin_amdgcn_mfma_f32_16x16x32_bf16(ah[i], bh, acc[i][j], 0, 0, 0);
                acc[i][j] = __builtin_amdgcn_mfma_f32_16x16x32_bf16(ah[i], bl, acc[i][j], 0, 0, 0);
                acc[i][j] = __builtin_amdgcn_mfma_f32_16x16x32_bf16(al[i], bh, acc[i][j], 0, 0, 0);
            }
        }
        __syncthreads();                         // frag reads done before overwrite
    }

    // epilogue: C/D layout col = lane&15, row = q*4 + reg  [m89-verified]
    float* Cb = C + (size_t)b * 1024 * NG + (size_t)bm0 * NG + bn0;
#pragma unroll
    for (int i = 0; i < 4; ++i)
#pragma unroll
        for (int j = 0; j < 4; ++j)
#pragma unroll
            for (int r = 0; r < 4; ++r)
                Cb[(size_t)(wm + i * 16 + q * 4 + r) * NG + wn + j * 16 + mf] = acc[i][j][r];
}

// ---------------------------------------------------------------------------
// Row softmax in place: one WAVE per row (no barriers). grid = 16384/4 blocks.
// ---------------------------------------------------------------------------
__global__ __launch_bounds__(256) void softmax_wave(float* __restrict__ S) {
    const int w = threadIdx.x >> 6, lane = threadIdx.x & 63;
    float* p = S + ((size_t)blockIdx.x * 4 + w) * LK;

    float4 v[4];
#pragma unroll
    for (int t = 0; t < 4; ++t) v[t] = *(float4*)(p + lane * 4 + t * 256);

    float m = -3.0e38f;
#pragma unroll
    for (int t = 0; t < 4; ++t)
        m = fmaxf(m, fmaxf(fmaxf(v[t].x, v[t].y), fmaxf(v[t].z, v[t].w)));
#pragma unroll
    for (int off = 1; off < 64; off <<= 1)
        m = fmaxf(m, __shfl_xor(m, off, 64));

    float s = 0.f;
#pragma unroll
    for (int t = 0; t < 4; ++t) {
        v[t].x = __expf(v[t].x - m); v[t].y = __expf(v[t].y - m);
        v[t].z = __expf(v[t].z - m); v[t].w = __expf(v[t].w - m);
        s += (v[t].x + v[t].y) + (v[t].z + v[t].w);
    }
#pragma unroll
    for (int off = 1; off < 64; off <<= 1)
        s += __shfl_xor(s, off, 64);

    const float inv = 1.0f / s;
#pragma unroll
    for (int t = 0; t < 4; ++t) {
        v[t].x *= inv; v[t].y *= inv; v[t].z *= inv; v[t].w *= inv;
        *(float4*)(p + lane * 4 + t * 256) = v[t];
    }
}

// ===========================================================================
// Fallback fp32 path — used only if ws_size is too small for Vt (33.6 MB)
// ===========================================================================
constexpr int BM = 64, BN = 64, BK = 16, PAD = 4;

__global__ __launch_bounds__(256) void gemm_qvt(const float* __restrict__ Q,
                                                const float* __restrict__ V,
                                                float* __restrict__ S) {
    __shared__ __align__(16) float sA[BK][BM + PAD];
    __shared__ __align__(16) float sB[BK][BN + PAD];
    const int b = blockIdx.z;
    const float* Qb = Q + (size_t)b * LQ * DD + (size_t)blockIdx.x * BM * DD;
    const float* Vb = V + (size_t)b * LK * DD + (size_t)blockIdx.y * BN * DD;
    float*       Sb = S + (size_t)b * LQ * LK;
    const int tid = threadIdx.x;
    const int tx = tid & 15, ty = tid >> 4;
    const int lr = tid >> 2, lc = (tid & 3) << 2;
    float acc[4][4] = {};
    for (int k0 = 0; k0 < DD; k0 += BK) {
        float4 qa = *(const float4*)(Qb + (size_t)lr * DD + k0 + lc);
        float4 va = *(const float4*)(Vb + (size_t)lr * DD + k0 + lc);
        __syncthreads();
        sA[lc + 0][lr] = qa.x; sA[lc + 1][lr] = qa.y; sA[lc + 2][lr] = qa.z; sA[lc + 3][lr] = qa.w;
        sB[lc + 0][lr] = va.x; sB[lc + 1][lr] = va.y; sB[lc + 2][lr] = va.z; sB[lc + 3][lr] = va.w;
        __syncthreads();
#pragma unroll
        for (int k = 0; k < BK; ++k) {
            float4 a4 = *(const float4*)&sA[k][ty << 2];
            float4 b4 = *(const float4*)&sB[k][tx << 2];
            float a[4] = {a4.x, a4.y, a4.z, a4.w};
            float bb[4] = {b4.x, b4.y, b4.z, b4.w};
#pragma unroll
            for (int i = 0; i < 4; ++i)
#pragma unroll
                for (int j = 0; j < 4; ++j) acc[i][j] = fmaf(a[i], bb[j], acc[i][j]);
        }
    }
    const int r0 = blockIdx.x * BM + (ty << 2), c0 = blockIdx.y * BN + (tx << 2);
#pragma unroll
    for (int i = 0; i < 4; ++i) {
        float4 o = {acc[i][0], acc[i][1], acc[i][2], acc[i][3]};
        *(float4*)(Sb + (size_t)(r0 + i) * LK + c0) = o;
    }
}

__global__ __launch_bounds__(256) void gemm_pv(const float* __restrict__ P,
                                               const float* __restrict__ V,
                                               float* __restrict__ C) {
    __shared__ __align__(16) float sA[BK][BM + PAD];
    __shared__ __align__(16) float sB[BK][BN + PAD];
    const int b = blockIdx.z;
    const float* Pb = P + (size_t)b * LQ * LK + (size_t)blockIdx.x * BM * LK;
    const float* Vb = V + (size_t)b * LK * DD;
    float*       Cb = C + (size_t)b * LQ * DD;
    const int tid = threadIdx.x;
    const int tx = tid & 15, ty = tid >> 4;
    const int lr = tid >> 2, lc = (tid & 3) << 2;
    const int bkr = tid >> 4, bcg = (tid & 15) << 2;
    const int n0 = blockIdx.y * BN;
    float acc[4][4] = {};
    for (int k0 = 0; k0 < LK; k0 += BK) {
        float4 pa = *(const float4*)(Pb + (size_t)lr * LK + k0 + lc);
        float4 vb = *(const float4*)(Vb + (size_t)(k0 + bkr) * DD + n0 + bcg);
        __syncthreads();
        sA[lc + 0][lr] = pa.x; sA[lc + 1][lr] = pa.y; sA[lc + 2][lr] = pa.z; sA[lc + 3][lr] = pa.w;
        *(float4*)&sB[bkr][bcg] = vb;
        __syncthreads();
#pragma unroll
        for (int k = 0; k < BK; ++k) {
            float4 a4 = *(const float4*)&sA[k][ty << 2];
            float4 b4 = *(const float4*)&sB[k][tx << 2];
            float a[4] = {a4.x, a4.y, a4.z, a4.w};
            float bb[4] = {b4.x, b4.y, b4.z, b4.w};
#pragma unroll
            for (int i = 0; i < 4; ++i)
#pragma unroll
                for (int j = 0; j < 4; ++j) acc[i][j] = fmaf(a[i], bb[j], acc[i][j]);
        }
    }
    const int r0 = blockIdx.x * BM + (ty << 2), c0 = n0 + (tx << 2);
#pragma unroll
    for (int i = 0; i < 4; ++i) {
        float4 o = {acc[i][0], acc[i][1], acc[i][2], acc[i][3]};
        *(float4*)(Cb + (size_t)(r0 + i) * DD + c0) = o;
    }
}

// ---------------------------------------------------------------------------
extern "C" void kernel_launch(void* const* d_in, const int* in_sizes, int n_in,
                              void* d_out, int out_size, void* d_ws, size_t ws_size,
                              hipStream_t stream) {
    const float* Q = (const float*)d_in[0];
    const float* V = (const float*)d_in[1];

    float* ctx  = (float*)d_out;                       // [16,1024,512]
    float* attn = ctx + (size_t)BATCH * LQ * DD;       // [16,1024,1024]

    const size_t vt_elems = (size_t)BATCH * DD * LK;   // 33.6 MB

    if (ws_size >= vt_elems * sizeof(float)) {
        float* Vt = (float*)d_ws;
        transpose_v<<<dim3(DD / 32, LK / 32, BATCH), 256, 0, stream>>>(V, Vt);
        // S = Q @ V^T : A = Q [1024,512], B = V [1024,512] (both k-contig)
        gemm_stage_split<DD, LK><<<dim3(8, 8, BATCH), 256, 0, stream>>>(Q, V, attn);
        softmax_wave<<<dim3(BATCH * LQ / 4), 256, 0, stream>>>(attn);
        // ctx = P @ V : A = P [1024,1024], B = Vt [512,1024] (both k-contig)
        gemm_stage_split<LK, DD><<<dim3(8, 4, BATCH), 256, 0, stream>>>(attn, Vt, ctx);
    } else {
        gemm_qvt<<<dim3(LQ / BM, LK / BN, BATCH), 256, 0, stream>>>(Q, V, attn);
        softmax_wave<<<dim3(BATCH * LQ / 4), 256, 0, stream>>>(attn);
        gemm_pv<<<dim3(LQ / BM, DD / BN, BATCH), 256, 0, stream>>>(attn, V, ctx);
    }
}